// Round 4
// baseline (177.969 us; speedup 1.0000x reference)
//
#include <hip/hip_runtime.h>
#include <hip/hip_bf16.h>

// Problem constants
#define DIM_X 256
#define DIM_E 256
#define DD    512          // DIM_X + DIM_E
#define NB    8            // batch
#define NN    2048         // sequence
#define SCALE 0.044194173824159216f   // (DIM_X+DIM_E)^-0.5
#define GRID  512          // 2 blocks/CU x 256 CU, fully resident

typedef __attribute__((ext_vector_type(8))) __bf16 bf16x8;
typedef __attribute__((ext_vector_type(4))) float  f32x4;
using bf16 = __hip_bfloat16;

__device__ __forceinline__ unsigned short f2bf(float f) {
  union { __hip_bfloat16 h; unsigned short u; } c;
  c.h = __float2bfloat16(f);
  return c.u;
}

// async global->LDS 16B copy. LDS dest must be wave-uniform base + lane*16.
__device__ __forceinline__ void async_lds16(const void* g, void* l) {
  using u32_as3 = __attribute__((address_space(3))) unsigned int;
  using u32_as1 = const __attribute__((address_space(1))) unsigned int;
  __builtin_amdgcn_global_load_lds(
      reinterpret_cast<u32_as1*>(reinterpret_cast<unsigned long long>(g)),
      reinterpret_cast<u32_as3*>(static_cast<unsigned int>(
          reinterpret_cast<unsigned long long>(l))),
      16, 0, 0);
}

// ---------------------------------------------------------------------------
// Grid barrier, TREE version. Round-1's single-counter barrier serialized 512
// agent-scope RMWs on one line (~45ns each ~= 23us/barrier -- the real cause
// of round-1's 108.7us). Two levels: 16 bucket counters (32 arrivals each, on
// independent 128B lines, parallel across buckets) -> 1 global counter (16
// arrivals) -> sense flip. Serial chain ~48 RMWs ~= 2-3us.
// Sense-reversing, self-restoring across graph replays (counters return to 0,
// sense flips; entry-read of sense is race-free because barrier k cannot
// complete before every block has entered it). Release chain: bucket reset ->
// acq_rel RMW on g_gcnt (RMW release sequence) -> release store of sense;
// waiters poll relaxed (every-64th fetch_add(0) forces the coherence point)
// then acquire-fence (buffer_inv).
// ---------------------------------------------------------------------------
#define NBUCKETS 16
#define BUCKET_SZ (GRID / NBUCKETS)  // 32
__device__ __align__(128) unsigned g_bcnt[NBUCKETS * 32] = {};
__device__ __align__(128) unsigned g_gcnt  = 0u;
__device__ __align__(128) unsigned g_sense = 0u;
__device__ __align__(128) unsigned g_wcnt   = 0u;  // 64-block mini barrier
__device__ __align__(128) unsigned g_wsense = 0u;

__device__ __forceinline__ void grid_sync(int bx) {
  __syncthreads();  // drains vmcnt/lgkm for all waves of the block
  if (threadIdx.x == 0) {
    unsigned s = __hip_atomic_load(&g_sense, __ATOMIC_RELAXED,
                                   __HIP_MEMORY_SCOPE_AGENT);
    unsigned* bc = &g_bcnt[(bx & (NBUCKETS - 1)) * 32];
    unsigned prev = __hip_atomic_fetch_add(bc, 1u, __ATOMIC_ACQ_REL,
                                           __HIP_MEMORY_SCOPE_AGENT);
    if (prev == BUCKET_SZ - 1) {           // last of bucket
      __hip_atomic_store(bc, 0u, __ATOMIC_RELAXED, __HIP_MEMORY_SCOPE_AGENT);
      unsigned gp = __hip_atomic_fetch_add(&g_gcnt, 1u, __ATOMIC_ACQ_REL,
                                           __HIP_MEMORY_SCOPE_AGENT);
      if (gp == NBUCKETS - 1) {            // last bucket
        __hip_atomic_store(&g_gcnt, 0u, __ATOMIC_RELAXED,
                           __HIP_MEMORY_SCOPE_AGENT);
        __hip_atomic_store(&g_sense, s ^ 1u, __ATOMIC_RELEASE,
                           __HIP_MEMORY_SCOPE_AGENT);
      }
    }
    unsigned n = 0;
    for (;;) {
      unsigned v = ((++n) & 63u)
                       ? __hip_atomic_load(&g_sense, __ATOMIC_RELAXED,
                                           __HIP_MEMORY_SCOPE_AGENT)
                       : __hip_atomic_fetch_add(&g_sense, 0u,
                                                __ATOMIC_RELAXED,
                                                __HIP_MEMORY_SCOPE_AGENT);
      if (v != s) break;
      __builtin_amdgcn_s_sleep(1);
    }
    __builtin_amdgcn_fence(__ATOMIC_ACQUIRE, "agent");
  }
  __syncthreads();
}

// mini-barrier: only blocks 0..63 participate (W pack -> W2T ordering).
__device__ __forceinline__ void w_sync() {
  __syncthreads();
  if (threadIdx.x == 0) {
    unsigned s = __hip_atomic_load(&g_wsense, __ATOMIC_RELAXED,
                                   __HIP_MEMORY_SCOPE_AGENT);
    unsigned prev = __hip_atomic_fetch_add(&g_wcnt, 1u, __ATOMIC_ACQ_REL,
                                           __HIP_MEMORY_SCOPE_AGENT);
    if (prev == 63u) {
      __hip_atomic_store(&g_wcnt, 0u, __ATOMIC_RELAXED,
                         __HIP_MEMORY_SCOPE_AGENT);
      __hip_atomic_store(&g_wsense, s ^ 1u, __ATOMIC_RELEASE,
                         __HIP_MEMORY_SCOPE_AGENT);
    } else {
      unsigned n = 0;
      for (;;) {
        unsigned v = ((++n) & 63u)
                         ? __hip_atomic_load(&g_wsense, __ATOMIC_RELAXED,
                                             __HIP_MEMORY_SCOPE_AGENT)
                         : __hip_atomic_fetch_add(&g_wsense, 0u,
                                                  __ATOMIC_RELAXED,
                                                  __HIP_MEMORY_SCOPE_AGENT);
        if (v != s) break;
        __builtin_amdgcn_s_sleep(1);
      }
    }
    __builtin_amdgcn_fence(__ATOMIC_ACQUIRE, "agent");
  }
  __syncthreads();
}

// ---------------------------------------------------------------------------
// One 32x32 pack job, WAVE-private (no __syncthreads): lane l owns half-row
// r0 = l>>1, 16 cols at c0 = (l&1)*16. LDS tile pad 40 floats/row: float4
// writes 16B-aligned; transposed scalar reads are 2-way-bank-aliased (free).
// Per-wave s_waitcnt lgkmcnt(0) fences write->read and read->next-job-write.
// ---------------------------------------------------------------------------
__device__ __forceinline__ void pack_tile(
    int j, float* wt, int lane, const float* __restrict__ x,
    const float* __restrict__ e, const float* __restrict__ Wq,
    const float* __restrict__ Wk, bf16* xb, bf16* VT, bf16* eb, bf16* ET,
    bf16* WqT, bf16* WkT) {
  const float* src; int ld;
  bf16 *dS = nullptr, *dT; int ldS = 0, ldT;
  if (j < 4096) {
    int b = j >> 9, r = (j >> 3) & 63, c = j & 7;
    src = x + ((long)b * NN + r * 32) * DIM_X + c * 32; ld = DIM_X;
    dS = xb + ((long)b * NN + r * 32) * DIM_X + c * 32; ldS = DIM_X;
    dT = VT + ((long)b * DIM_X + c * 32) * NN + r * 32; ldT = NN;
  } else if (j < 4608) {
    int i = j - 4096, r = i >> 3, c = i & 7;
    src = e + ((long)r * 32) * DIM_E + c * 32; ld = DIM_E;
    dS = eb + ((long)r * 32) * DIM_E + c * 32; ldS = DIM_E;
    dT = ET + ((long)c * 32) * NN + r * 32; ldT = NN;
  } else if (j < 4864) {
    int i = j - 4608, r = i >> 4, c = i & 15;
    src = Wq + ((long)r * 32) * DD + c * 32; ld = DD;
    dT = WqT + ((long)c * 32) * DD + r * 32; ldT = DD;
  } else {
    int i = j - 4864, r = i >> 4, c = i & 15;
    src = Wk + ((long)r * 32) * DD + c * 32; ld = DD;
    dT = WkT + ((long)c * 32) * DD + r * 32; ldT = DD;
  }
  const int r0 = lane >> 1;
  const int c0 = (lane & 1) << 4;
  const float* s0 = src + (long)r0 * ld + c0;
  float4 v0 = *(const float4*)(s0 + 0);
  float4 v1 = *(const float4*)(s0 + 4);
  float4 v2 = *(const float4*)(s0 + 8);
  float4 v3 = *(const float4*)(s0 + 12);
  if (dS) {
    unsigned short* d = (unsigned short*)dS + (long)r0 * ldS + c0;
    ushort4 o;
    o.x = f2bf(v0.x); o.y = f2bf(v0.y); o.z = f2bf(v0.z); o.w = f2bf(v0.w);
    *(ushort4*)(d + 0) = o;
    o.x = f2bf(v1.x); o.y = f2bf(v1.y); o.z = f2bf(v1.z); o.w = f2bf(v1.w);
    *(ushort4*)(d + 4) = o;
    o.x = f2bf(v2.x); o.y = f2bf(v2.y); o.z = f2bf(v2.z); o.w = f2bf(v2.w);
    *(ushort4*)(d + 8) = o;
    o.x = f2bf(v3.x); o.y = f2bf(v3.y); o.z = f2bf(v3.z); o.w = f2bf(v3.w);
    *(ushort4*)(d + 12) = o;
  }
  // prior job's LDS reads must retire before overwriting the private tile
  asm volatile("s_waitcnt lgkmcnt(0)" ::: "memory");
  float* w0 = wt + r0 * 40 + c0;
  *(float4*)(w0 + 0) = v0; *(float4*)(w0 + 4) = v1;
  *(float4*)(w0 + 8) = v2; *(float4*)(w0 + 12) = v3;
  asm volatile("s_waitcnt lgkmcnt(0)" ::: "memory");
  __builtin_amdgcn_sched_barrier(0);
  unsigned short* dt = (unsigned short*)dT + (long)r0 * ldT + c0;
  ushort4 o;
  o.x = f2bf(wt[(c0 + 0) * 40 + r0]); o.y = f2bf(wt[(c0 + 1) * 40 + r0]);
  o.z = f2bf(wt[(c0 + 2) * 40 + r0]); o.w = f2bf(wt[(c0 + 3) * 40 + r0]);
  *(ushort4*)(dt + 0) = o;
  o.x = f2bf(wt[(c0 + 4) * 40 + r0]); o.y = f2bf(wt[(c0 + 5) * 40 + r0]);
  o.z = f2bf(wt[(c0 + 6) * 40 + r0]); o.w = f2bf(wt[(c0 + 7) * 40 + r0]);
  *(ushort4*)(dt + 4) = o;
  o.x = f2bf(wt[(c0 + 8) * 40 + r0]); o.y = f2bf(wt[(c0 + 9) * 40 + r0]);
  o.z = f2bf(wt[(c0 + 10) * 40 + r0]); o.w = f2bf(wt[(c0 + 11) * 40 + r0]);
  *(ushort4*)(dt + 8) = o;
  o.x = f2bf(wt[(c0 + 12) * 40 + r0]); o.y = f2bf(wt[(c0 + 13) * 40 + r0]);
  o.z = f2bf(wt[(c0 + 14) * 40 + r0]); o.w = f2bf(wt[(c0 + 15) * 40 + r0]);
  *(ushort4*)(dt + 12) = o;
}

// ---------------------------------------------------------------------------
// One BMxBN tile of C = alpha * Acat @ Bcat^T (operands K-major bf16).
// Proven dbuf version (rounds 2-3): 4 waves 2x2, 16x16x32 MFMA, XOR-swizzled
// LDS, global_load_lds width-16 staging, stage(t+1) before compute(t), one
// barrier per K-step. smem = 2*(BM+BN)*BKt*2 bytes.
// ---------------------------------------------------------------------------
template <int BM, int BN, int BKt, bool OUT_BF16, int ASPLIT, int BSPLIT>
__device__ void gemm_tile(const bf16* __restrict__ A0,
                          const bf16* __restrict__ A1,
                          const bf16* __restrict__ B0,
                          const bf16* __restrict__ B1, void* __restrict__ Cv,
                          int K, int lda, int ldb, int ldc, float alpha,
                          char* smem) {
  constexpr int CPT  = BKt / 8;
  constexpr int KS   = BKt / 32;
  constexpr int WTM  = BM / 2, WTN = BN / 2;
  constexpr int IM   = WTM / 16, IN = WTN / 16;
  constexpr int CA   = BM * CPT, CB = BN * CPT;
  constexpr int BUFB = (BM + BN) * BKt * 2;

  const int tid  = threadIdx.x;
  const int lane = tid & 63;
  const int wave = tid >> 6;
  const int lm   = lane & 15;
  const int quad = lane >> 4;
  const int wm   = (wave >> 1) * WTM;
  const int wn   = (wave & 1) * WTN;

  auto stage = [&](int t, int buf) {
    const int k0 = t * BKt;
    const bf16* Ak = A0; int ka = k0;
    if (ASPLIT > 0 && k0 >= ASPLIT) { Ak = A1; ka = k0 - ASPLIT; }
    const bf16* Bk = B0; int kb = k0;
    if (BSPLIT > 0 && k0 >= BSPLIT) { Bk = B1; kb = k0 - BSPLIT; }
    bf16* sA = (bf16*)(smem + (size_t)buf * BUFB);
    bf16* sB = sA + BM * BKt;
#pragma unroll
    for (int c = tid; c < CA; c += 256) {
      int row = c / CPT;
      int cb  = (c % CPT) ^ (row % CPT);
      async_lds16(Ak + (long)row * lda + ka + cb * 8, sA + (size_t)c * 8);
    }
#pragma unroll
    for (int c = tid; c < CB; c += 256) {
      int row = c / CPT;
      int cb  = (c % CPT) ^ (row % CPT);
      async_lds16(Bk + (long)row * ldb + kb + cb * 8, sB + (size_t)c * 8);
    }
  };

  f32x4 acc[IM][IN];
#pragma unroll
  for (int i = 0; i < IM; i++)
#pragma unroll
    for (int j = 0; j < IN; j++) acc[i][j] = (f32x4){0.f, 0.f, 0.f, 0.f};

  const int nt = K / BKt;
  stage(0, 0);
  __syncthreads();
  int cur = 0;
  for (int t = 0; t < nt; ++t) {
    if (t + 1 < nt) stage(t + 1, cur ^ 1);
    const bf16* sA = (const bf16*)(smem + (size_t)cur * BUFB);
    const bf16* sB = sA + BM * BKt;
    bf16x8 af[KS][IM], bfr[KS][IN];
#pragma unroll
    for (int s = 0; s < KS; s++) {
#pragma unroll
      for (int i = 0; i < IM; i++) {
        int r = wm + i * 16 + lm;
        af[s][i] = *(const bf16x8*)&sA[r * BKt +
                                       (((s * 4 + quad) ^ (r % CPT)) * 8)];
      }
#pragma unroll
      for (int j = 0; j < IN; j++) {
        int r = wn + j * 16 + lm;
        bfr[s][j] = *(const bf16x8*)&sB[r * BKt +
                                        (((s * 4 + quad) ^ (r % CPT)) * 8)];
      }
    }
#pragma unroll
    for (int s = 0; s < KS; s++)
#pragma unroll
      for (int i = 0; i < IM; i++)
#pragma unroll
        for (int j = 0; j < IN; j++)
          acc[i][j] = __builtin_amdgcn_mfma_f32_16x16x32_bf16(
              af[s][i], bfr[s][j], acc[i][j], 0, 0, 0);
    __syncthreads();
    cur ^= 1;
  }

  // C/D layout (16x16): col = lane&15, row = (lane>>4)*4 + reg  [m89-verified]
  const int baseRow = wm + quad * 4;
  const int baseCol = wn + lm;
  if (OUT_BF16) {
    bf16* Cb = (bf16*)Cv;
#pragma unroll
    for (int i = 0; i < IM; i++)
#pragma unroll
      for (int r = 0; r < 4; r++) {
        int row = baseRow + i * 16 + r;
#pragma unroll
        for (int j = 0; j < IN; j++)
          Cb[(long)row * ldc + baseCol + j * 16] =
              __float2bfloat16(acc[i][j][r] * alpha);
      }
  } else {
    float* Cf = (float*)Cv;
#pragma unroll
    for (int i = 0; i < IM; i++)
#pragma unroll
      for (int r = 0; r < 4; r++) {
        int row = baseRow + i * 16 + r;
#pragma unroll
        for (int j = 0; j < IN; j++)
          Cf[(long)row * ldc + baseCol + j * 16] = acc[i][j][r] * alpha;
      }
  }
}

// ---------------------------------------------------------------------------
// Fused pipeline v2: one launch, 512 blocks, tree barriers.
//   phase0: pack. Blocks 64..511 stream the 4608 x/e jobs wave-privately
//           (1792 waves, 2-3 jobs each, ZERO block barriers). Blocks 0..63
//           pack the 512 W jobs (256 waves x 2), mini-barrier, then compute
//           W2T = WqT @ WkT^T (64x64, K=512) INSIDE the pack window --
//           phase1 has no W2T tail.
//   phase1: M half-K partials, 64x64 tiles, 512 jobs (b,mt,nt,kh), K=1024
//           (round-2-verified mapping), b = bx&7 XCD-affine.
//   phase2: R = SCALE*(M1+M2)@W2T^T as K-concat GEMM K=1024 (verified).
//   phase3: out = [xb|eb] @ R^T, 64x128 tiles, fp32 out (verified).
// ---------------------------------------------------------------------------
__global__ __launch_bounds__(256, 2) void fused2_k(
    const float* __restrict__ x, const float* __restrict__ e,
    const float* __restrict__ Wq, const float* __restrict__ Wk,
    bf16* __restrict__ xb, bf16* __restrict__ VT, bf16* __restrict__ eb,
    bf16* __restrict__ ET, bf16* __restrict__ WqT, bf16* __restrict__ WkT,
    bf16* __restrict__ W2T, bf16* __restrict__ M1, bf16* __restrict__ M2,
    bf16* __restrict__ R, float* __restrict__ out) {
  __shared__ __align__(16) char smem[49152];
  const int bx   = blockIdx.x;
  const int tid  = threadIdx.x;
  const int lane = tid & 63;
  const int wv   = tid >> 6;

  // ---- phase 0: pack ----
  {
    float* wt = (float*)(smem + wv * 5120);  // 32x40 fp32, wave-private
    if (bx < 64) {
      const int wwave = bx * 4 + wv;         // 0..255
      pack_tile(4608 + wwave * 2 + 0, wt, lane, x, e, Wq, Wk, xb, VT, eb, ET,
                WqT, WkT);
      pack_tile(4608 + wwave * 2 + 1, wt, lane, x, e, Wq, Wk, xb, VT, eb, ET,
                WqT, WkT);
      w_sync();  // all 512 W jobs done across blocks 0..63
      int r2 = bx >> 3, c2 = bx & 7;
      gemm_tile<64, 64, 64, true, 0, 0>(
          WqT + (long)r2 * 64 * DD, nullptr, WkT + (long)c2 * 64 * DD,
          nullptr, W2T + (long)r2 * 64 * DD + c2 * 64, DD, DD, DD, DD, 1.0f,
          smem);
    } else {
      const int xwave = (bx - 64) * 4 + wv;  // 0..1791
      for (int j = xwave; j < 4608; j += 1792)
        pack_tile(j, wt, lane, x, e, Wq, Wk, xb, VT, eb, ET, WqT, WkT);
    }
  }
  grid_sync(bx);

  // ---- phase 1: M split-K partials (round-2-verified mapping) ----
  {
    const int b   = bx & 7;
    const int idx = bx >> 3;              // 0..63
    const int kh  = idx & 1;              // K half
    const int mt  = (idx >> 1) & 3;       // row tile (4 x 64 = 256)
    const int nt  = idx >> 3;             // col tile (8 x 64 = 512)
    const bf16* A = VT + (long)b * DIM_X * NN + (long)mt * 64 * NN + kh * 1024;
    const bf16* B = (nt < 4)
        ? VT + (long)b * DIM_X * NN + (long)nt * 64 * NN + kh * 1024
        : ET + (long)(nt - 4) * 64 * NN + kh * 1024;
    bf16* C = (kh ? M2 : M1) + (long)b * DIM_X * DD + (long)mt * 64 * DD +
              nt * 64;
    gemm_tile<64, 64, 64, true, 0, 0>(A, nullptr, B, nullptr, C, 1024, NN,
                                      NN, DD, 1.0f, smem);
  }
  grid_sync(bx);

  // ---- phase 2: R = SCALE * (M1+M2) @ W2T^T (K-concat, verified) ----
  {
    const int b = bx & 7, r = (bx >> 3) & 7, c = bx >> 6;
    const bf16* a0 = M1 + (long)b * DIM_X * DD + (long)r * 32 * DD;
    const bf16* a1 = M2 + (long)b * DIM_X * DD + (long)r * 32 * DD;
    const bf16* w  = W2T + (long)c * 64 * DD;
    gemm_tile<32, 64, 128, true, 512, 512>(
        a0, a1, w, w,
        R + (long)b * DIM_X * DD + (long)r * 32 * DD + c * 64, 1024, DD, DD,
        DD, SCALE, smem);
  }
  grid_sync(bx);

  // ---- phase 3: out = [xb|eb] @ R^T (fp32 out, verified) ----
  {
    const int b = bx & 7, m = (bx >> 3) & 31, n = (bx >> 8) & 1;
    gemm_tile<64, 128, 64, false, 256, 0>(
        xb + (long)b * NN * DIM_X + (long)m * 64 * DIM_X,
        eb + (long)m * 64 * DIM_E,
        R + (long)b * DIM_X * DD + (long)n * 128 * DD, nullptr,
        out + (long)b * NN * DIM_X + (long)m * 64 * DIM_X + n * 128, DD,
        DIM_X, DD, DIM_X, 1.0f, smem);
  }
}

// ---------------------------------------------------------------------------

extern "C" void kernel_launch(void* const* d_in, const int* in_sizes, int n_in,
                              void* d_out, int out_size, void* d_ws,
                              size_t ws_size, hipStream_t stream) {
  const float* x  = (const float*)d_in[0];  // (8, 2048, 256)
  const float* e  = (const float*)d_in[1];  // (2048, 256)
  const float* Wq = (const float*)d_in[2];  // (512, 512)
  const float* Wk = (const float*)d_in[3];  // (512, 512)
  float* out = (float*)d_out;               // (8, 2048, 256)

  char* ws = (char*)d_ws;
  size_t off = 0;
  auto alloc = [&](size_t bytes) {
    void* p = ws + off;
    off += (bytes + 255) & ~(size_t)255;
    return p;
  };

  bf16* xb  = (bf16*)alloc((size_t)NB * NN * DIM_X * 2);  // 8.4 MB
  bf16* VT  = (bf16*)alloc((size_t)NB * DIM_X * NN * 2);  // 8.4 MB
  bf16* eb  = (bf16*)alloc((size_t)NN * DIM_E * 2);       // 1 MB
  bf16* ET  = (bf16*)alloc((size_t)DIM_E * NN * 2);       // 1 MB
  bf16* WqT = (bf16*)alloc((size_t)DD * DD * 2);          // 0.5 MB
  bf16* WkT = (bf16*)alloc((size_t)DD * DD * 2);          // 0.5 MB
  bf16* W2T = (bf16*)alloc((size_t)DD * DD * 2);          // 0.5 MB
  bf16* M1  = (bf16*)alloc((size_t)NB * DIM_X * DD * 2);  // 2 MB
  bf16* M2  = (bf16*)alloc((size_t)NB * DIM_X * DD * 2);  // 2 MB
  bf16* R   = (bf16*)alloc((size_t)NB * DIM_X * DD * 2);  // 2 MB

  fused2_k<<<GRID, 256, 0, stream>>>(x, e, Wq, Wk, xb, VT, eb, ET, WqT, WkT,
                                     W2T, M1, M2, R, out);
}

// Round 5
// 105.294 us; speedup vs baseline: 1.6902x; 1.6902x over previous
//
#include <hip/hip_runtime.h>
#include <hip/hip_bf16.h>

// Problem constants
#define DIM_X 256
#define DIM_E 256
#define DD    512          // DIM_X + DIM_E
#define NB    8            // batch
#define NN    2048         // sequence
#define SCALE 0.044194173824159216f   // (DIM_X+DIM_E)^-0.5

typedef __attribute__((ext_vector_type(8))) __bf16 bf16x8;
typedef __attribute__((ext_vector_type(4))) float  f32x4;
using bf16 = __hip_bfloat16;

__device__ __forceinline__ unsigned short f2bf(float f) {
  union { __hip_bfloat16 h; unsigned short u; } c;
  c.h = __float2bfloat16(f);
  return c.u;
}

// async global->LDS 16B copy. LDS dest must be wave-uniform base + lane*16.
__device__ __forceinline__ void async_lds16(const void* g, void* l) {
  using u32_as3 = __attribute__((address_space(3))) unsigned int;
  using u32_as1 = const __attribute__((address_space(1))) unsigned int;
  __builtin_amdgcn_global_load_lds(
      reinterpret_cast<u32_as1*>(reinterpret_cast<unsigned long long>(g)),
      reinterpret_cast<u32_as3*>(static_cast<unsigned int>(
          reinterpret_cast<unsigned long long>(l))),
      16, 0, 0);
}

// ---------------------------------------------------------------------------
// pack: 5120 32x32-tile jobs, one per block.
// XCD AFFINITY (this round's change): x-jobs (b,r,c) are assigned to blocks
// with bx&7 == b, so VT_b / xb_b are WRITTEN from XCD b's CUs and land in
// XCD b's L2 -- phase1/phase3 blocks (also pinned bx&7==b) then read them
// L2-locally instead of cross-XCD. (phase2 already had this property: M1/M2
// are produced and consumed by bx&7==b blocks.)
//   blocks [0,4096):    x-job b=bx&7, slot=bx>>3: r=slot>>3, c=slot&7
//                       -> xb (straight bf16) + VT (transpose)
//   blocks [4096,4608): e -> eb (straight) + ET (transpose)
//   blocks [4608,4864): Wq -> WqT (transpose)
//   blocks [4864,5120): Wk -> WkT (transpose)
// ---------------------------------------------------------------------------
__global__ __launch_bounds__(256, 4) void pack_k(
    const float* __restrict__ x, const float* __restrict__ e,
    const float* __restrict__ Wq, const float* __restrict__ Wk, bf16* xb,
    bf16* VT, bf16* eb, bf16* ET, bf16* WqT, bf16* WkT) {
  __shared__ float tile[32][33];
  const int tid  = threadIdx.x;
  const int lrow = tid >> 3;        // 0..31 (load row)
  const int lc4  = (tid & 7) * 4;   // float4 col
  const int j    = blockIdx.x;
  const float* src; int ld;
  bf16 *dS = nullptr, *dT; int ldS = 0, ldT;
  if (j < 4096) {
    int b = j & 7;                  // XCD-affine: block XCD == batch
    int slot = j >> 3;              // 0..511
    int r = slot >> 3, c = slot & 7;
    src = x + ((long)b * NN + r * 32) * DIM_X + c * 32; ld = DIM_X;
    dS = xb + ((long)b * NN + r * 32) * DIM_X + c * 32; ldS = DIM_X;
    dT = VT + ((long)b * DIM_X + c * 32) * NN + r * 32; ldT = NN;
  } else if (j < 4608) {
    int i = j - 4096, r = i >> 3, c = i & 7;
    src = e + ((long)r * 32) * DIM_E + c * 32; ld = DIM_E;
    dS = eb + ((long)r * 32) * DIM_E + c * 32; ldS = DIM_E;
    dT = ET + ((long)c * 32) * NN + r * 32; ldT = NN;
  } else if (j < 4864) {
    int i = j - 4608, r = i >> 4, c = i & 15;
    src = Wq + ((long)r * 32) * DD + c * 32; ld = DD;
    dT = WqT + ((long)c * 32) * DD + r * 32; ldT = DD;
  } else {
    int i = j - 4864, r = i >> 4, c = i & 15;
    src = Wk + ((long)r * 32) * DD + c * 32; ld = DD;
    dT = WkT + ((long)c * 32) * DD + r * 32; ldT = DD;
  }
  float4 v = *(const float4*)(src + (long)lrow * ld + lc4);
  if (dS) {
    ushort4 o;
    o.x = f2bf(v.x); o.y = f2bf(v.y); o.z = f2bf(v.z); o.w = f2bf(v.w);
    *(ushort4*)((unsigned short*)dS + (long)lrow * ldS + lc4) = o;
  }
  tile[lrow][lc4 + 0] = v.x; tile[lrow][lc4 + 1] = v.y;
  tile[lrow][lc4 + 2] = v.z; tile[lrow][lc4 + 3] = v.w;
  __syncthreads();
  {
    ushort4 o;
    o.x = f2bf(tile[lc4 + 0][lrow]);
    o.y = f2bf(tile[lc4 + 1][lrow]);
    o.z = f2bf(tile[lc4 + 2][lrow]);
    o.w = f2bf(tile[lc4 + 3][lrow]);
    *(ushort4*)((unsigned short*)dT + (long)lrow * ldT + lc4) = o;
  }
}

// ---------------------------------------------------------------------------
// One BMxBN tile of C = alpha * Acat @ Bcat^T (operands K-major bf16).
// 4 waves 2x2, wave tile (BM/2)x(BN/2), 16x16x32 MFMA, XOR-swizzled LDS,
// global_load_lds width-16 staging, double-buffered (stage t+1 issued before
// compute of t; the single end-of-step barrier's vmcnt(0) drains it after
// the prefetch latency hid under the MFMAs).
// ASPLIT>0: for k>=ASPLIT read A1 at k-ASPLIT (K-concatenation of A0|A1).
// BSPLIT>0: same for B0|B1 (B1==B0 gives a K-repeated B).
// smem must be 2*(BM+BN)*BKt*2 bytes.
// ---------------------------------------------------------------------------
template <int BM, int BN, int BKt, bool OUT_BF16, int ASPLIT, int BSPLIT>
__device__ void gemm_tile(const bf16* __restrict__ A0,
                          const bf16* __restrict__ A1,
                          const bf16* __restrict__ B0,
                          const bf16* __restrict__ B1, void* __restrict__ Cv,
                          int K, int lda, int ldb, int ldc, float alpha,
                          char* smem) {
  constexpr int CPT  = BKt / 8;      // 16B chunks per row
  constexpr int KS   = BKt / 32;     // MFMA k-steps per staged tile
  constexpr int WTM  = BM / 2, WTN = BN / 2;
  constexpr int IM   = WTM / 16, IN = WTN / 16;
  constexpr int CA   = BM * CPT, CB = BN * CPT;
  constexpr int BUFB = (BM + BN) * BKt * 2;  // bytes per LDS buffer

  const int tid  = threadIdx.x;
  const int lane = tid & 63;
  const int wave = tid >> 6;
  const int lm   = lane & 15;
  const int quad = lane >> 4;
  const int wm   = (wave >> 1) * WTM;
  const int wn   = (wave & 1) * WTN;

  auto stage = [&](int t, int buf) {
    const int k0 = t * BKt;
    const bf16* Ak = A0; int ka = k0;
    if (ASPLIT > 0 && k0 >= ASPLIT) { Ak = A1; ka = k0 - ASPLIT; }
    const bf16* Bk = B0; int kb = k0;
    if (BSPLIT > 0 && k0 >= BSPLIT) { Bk = B1; kb = k0 - BSPLIT; }
    bf16* sA = (bf16*)(smem + (size_t)buf * BUFB);
    bf16* sB = sA + BM * BKt;
#pragma unroll
    for (int c = tid; c < CA; c += 256) {
      int row = c / CPT;
      int cb  = (c % CPT) ^ (row % CPT);
      async_lds16(Ak + (long)row * lda + ka + cb * 8, sA + (size_t)c * 8);
    }
#pragma unroll
    for (int c = tid; c < CB; c += 256) {
      int row = c / CPT;
      int cb  = (c % CPT) ^ (row % CPT);
      async_lds16(Bk + (long)row * ldb + kb + cb * 8, sB + (size_t)c * 8);
    }
  };

  f32x4 acc[IM][IN];
#pragma unroll
  for (int i = 0; i < IM; i++)
#pragma unroll
    for (int j = 0; j < IN; j++) acc[i][j] = (f32x4){0.f, 0.f, 0.f, 0.f};

  const int nt = K / BKt;
  stage(0, 0);
  __syncthreads();  // drains vmcnt(0): tile 0 resident
  int cur = 0;
  for (int t = 0; t < nt; ++t) {
    if (t + 1 < nt) stage(t + 1, cur ^ 1);  // prefetch overlaps compute below
    const bf16* sA = (const bf16*)(smem + (size_t)cur * BUFB);
    const bf16* sB = sA + BM * BKt;
    bf16x8 af[KS][IM], bfr[KS][IN];
#pragma unroll
    for (int s = 0; s < KS; s++) {
#pragma unroll
      for (int i = 0; i < IM; i++) {
        int r = wm + i * 16 + lm;
        af[s][i] = *(const bf16x8*)&sA[r * BKt +
                                       (((s * 4 + quad) ^ (r % CPT)) * 8)];
      }
#pragma unroll
      for (int j = 0; j < IN; j++) {
        int r = wn + j * 16 + lm;
        bfr[s][j] = *(const bf16x8*)&sB[r * BKt +
                                        (((s * 4 + quad) ^ (r % CPT)) * 8)];
      }
    }
#pragma unroll
    for (int s = 0; s < KS; s++)
#pragma unroll
      for (int i = 0; i < IM; i++)
#pragma unroll
        for (int j = 0; j < IN; j++)
          acc[i][j] = __builtin_amdgcn_mfma_f32_16x16x32_bf16(
              af[s][i], bfr[s][j], acc[i][j], 0, 0, 0);
    __syncthreads();  // readers done with buf cur; prefetch into cur^1 drained
    cur ^= 1;
  }

  // C/D layout (16x16): col = lane&15, row = (lane>>4)*4 + reg  [m89-verified]
  const int baseRow = wm + quad * 4;
  const int baseCol = wn + lm;
  if (OUT_BF16) {
    bf16* Cb = (bf16*)Cv;
#pragma unroll
    for (int i = 0; i < IM; i++)
#pragma unroll
      for (int r = 0; r < 4; r++) {
        int row = baseRow + i * 16 + r;
#pragma unroll
        for (int j = 0; j < IN; j++)
          Cb[(long)row * ldc + baseCol + j * 16] =
              __float2bfloat16(acc[i][j][r] * alpha);
      }
  } else {
    float* Cf = (float*)Cv;
#pragma unroll
    for (int i = 0; i < IM; i++)
#pragma unroll
      for (int r = 0; r < 4; r++) {
        int row = baseRow + i * 16 + r;
#pragma unroll
        for (int j = 0; j < IN; j++)
          Cf[(long)row * ldc + baseCol + j * 16] = acc[i][j][r] * alpha;
      }
  }
}

// ---------------------------------------------------------------------------
// phase1 (320 blocks, 48KB LDS -> up to 3/CU so the 64 W2T blocks co-schedule
// with M blocks instead of serializing):
//   blocks [0,256):   M half-K partials, 128x64 tiles (16 MFMA / 12 ds_read
//                     per wave-step), 256 jobs (b, mt in 2 x 128rows,
//                     nt in 8 x 64cols, kh in 2), K=1024 each, reduced in
//                     phase2 via K-concat. b = bx&7: with the pack remap,
//                     VT_b is now resident in THIS XCD's L2.
//   blocks [256,320): W2T = WqT @ WkT^T (64x64, K=512)
// ---------------------------------------------------------------------------
__global__ __launch_bounds__(256, 2) void phase1_k(
    const bf16* VT, const bf16* ET, const bf16* WqT, const bf16* WkT,
    bf16* M1, bf16* M2, bf16* W2T) {
  __shared__ __align__(16) char smem[49152];
  const int bx = blockIdx.x;
  if (bx < 256) {
    const int b   = bx & 7;
    const int idx = bx >> 3;              // 0..31
    const int kh  = idx & 1;              // K half
    const int mt  = (idx >> 1) & 1;       // row tile (2 x 128 = 256)
    const int nt  = idx >> 2;             // col tile (8 x 64 = 512)
    const bf16* A = VT + (long)b * DIM_X * NN + (long)mt * 128 * NN +
                    kh * 1024;
    const bf16* B = (nt < 4)
        ? VT + (long)b * DIM_X * NN + (long)nt * 64 * NN + kh * 1024
        : ET + (long)(nt - 4) * 64 * NN + kh * 1024;
    bf16* C = (kh ? M2 : M1) + (long)b * DIM_X * DD + (long)mt * 128 * DD +
              nt * 64;
    gemm_tile<128, 64, 64, true, 0, 0>(A, nullptr, B, nullptr, C, 1024, NN,
                                       NN, DD, 1.0f, smem);
  } else {
    const int i = bx - 256;
    int r2 = i >> 3, c2 = i & 7;
    gemm_tile<64, 64, 64, true, 0, 0>(
        WqT + (long)r2 * 64 * DD, nullptr, WkT + (long)c2 * 64 * DD, nullptr,
        W2T + (long)r2 * 64 * DD + c2 * 64, DD, DD, DD, DD, 1.0f, smem);
  }
}

// ---------------------------------------------------------------------------
// phase2 (512 blocks): R = SCALE * (M1+M2) @ W2T^T as K-concat GEMM K=1024
// ([M1|M2] @ [W2T|W2T]^T, ASPLIT=BSPLIT=512; verified in rounds 1-4).
// 32x64 tiles, BK=128 dbuf (48KB), 2/CU resident. M1/M2 producer (phase1)
// and consumer here are both bx&7==b -> already XCD-L2-local.
// ---------------------------------------------------------------------------
__global__ __launch_bounds__(256, 3) void phase2_k(const bf16* M1,
                                                   const bf16* M2,
                                                   const bf16* W2T, bf16* R) {
  __shared__ __align__(16) char smem[49152];
  const int bx = blockIdx.x;
  const int b = bx & 7, r = (bx >> 3) & 7, c = bx >> 6;
  const bf16* a0 = M1 + (long)b * DIM_X * DD + (long)r * 32 * DD;
  const bf16* a1 = M2 + (long)b * DIM_X * DD + (long)r * 32 * DD;
  const bf16* w  = W2T + (long)c * 64 * DD;
  gemm_tile<32, 64, 128, true, 512, 512>(
      a0, a1, w, w, R + (long)b * DIM_X * DD + (long)r * 32 * DD + c * 64,
      1024, DD, DD, DD, SCALE, smem);
}

// ---------------------------------------------------------------------------
// phase3 (256 blocks): out = [xb|eb] @ R^T, 128x128 tiles (m97 per-wave
// shape: 64x64 wave tile, 32 MFMA / 16 ds_read per step), BK=64 dbuf = 64KB
// LDS, fp32 out, 1 block/CU. b = bx&7: xb_b (pack remap) and R_b (phase2)
// are now both XCD-L2-local.
// ---------------------------------------------------------------------------
__global__ __launch_bounds__(256, 2) void phase3_k(const bf16* xb,
                                                   const bf16* eb,
                                                   const bf16* R, float* out) {
  __shared__ __align__(16) char smem[65536];
  const int bx = blockIdx.x;
  const int b = bx & 7, m = (bx >> 3) & 15, n = (bx >> 7) & 1;
  gemm_tile<128, 128, 64, false, 256, 0>(
      xb + (long)b * NN * DIM_X + (long)m * 128 * DIM_X,
      eb + (long)m * 128 * DIM_E,
      R + (long)b * DIM_X * DD + (long)n * 128 * DD, nullptr,
      out + (long)b * NN * DIM_X + (long)m * 128 * DIM_X + n * 128, DD,
      DIM_X, DD, DIM_X, 1.0f, smem);
}

// ---------------------------------------------------------------------------

extern "C" void kernel_launch(void* const* d_in, const int* in_sizes, int n_in,
                              void* d_out, int out_size, void* d_ws,
                              size_t ws_size, hipStream_t stream) {
  const float* x  = (const float*)d_in[0];  // (8, 2048, 256)
  const float* e  = (const float*)d_in[1];  // (2048, 256)
  const float* Wq = (const float*)d_in[2];  // (512, 512)
  const float* Wk = (const float*)d_in[3];  // (512, 512)
  float* out = (float*)d_out;               // (8, 2048, 256)

  char* ws = (char*)d_ws;
  size_t off = 0;
  auto alloc = [&](size_t bytes) {
    void* p = ws + off;
    off += (bytes + 255) & ~(size_t)255;
    return p;
  };

  bf16* xb  = (bf16*)alloc((size_t)NB * NN * DIM_X * 2);  // 8.4 MB
  bf16* VT  = (bf16*)alloc((size_t)NB * DIM_X * NN * 2);  // 8.4 MB
  bf16* eb  = (bf16*)alloc((size_t)NN * DIM_E * 2);       // 1 MB
  bf16* ET  = (bf16*)alloc((size_t)DIM_E * NN * 2);       // 1 MB
  bf16* WqT = (bf16*)alloc((size_t)DD * DD * 2);          // 0.5 MB
  bf16* WkT = (bf16*)alloc((size_t)DD * DD * 2);          // 0.5 MB
  bf16* W2T = (bf16*)alloc((size_t)DD * DD * 2);          // 0.5 MB
  bf16* M1  = (bf16*)alloc((size_t)NB * DIM_X * DD * 2);  // 2 MB
  bf16* M2  = (bf16*)alloc((size_t)NB * DIM_X * DD * 2);  // 2 MB
  bf16* R   = (bf16*)alloc((size_t)NB * DIM_X * DD * 2);  // 2 MB

  pack_k<<<5120, 256, 0, stream>>>(x, e, Wq, Wk, xb, VT, eb, ET, WqT, WkT);
  phase1_k<<<320, 256, 0, stream>>>(VT, ET, WqT, WkT, M1, M2, W2T);
  phase2_k<<<512, 256, 0, stream>>>(M1, M2, W2T, R);
  phase3_k<<<256, 256, 0, stream>>>(xb, eb, R, out);
}